// Round 1
// baseline (429.926 us; speedup 1.0000x reference)
//
#include <hip/hip_runtime.h>
#include <hip/hip_cooperative_groups.h>
#include <hip/hip_bf16.h>

namespace cg = cooperative_groups;

typedef __bf16 bf16x8 __attribute__((ext_vector_type(8)));
typedef __bf16 bf16x4 __attribute__((ext_vector_type(4)));
typedef float f32x4 __attribute__((ext_vector_type(4)));

#define KDIM 4096   // K = 128 blocks * 32
#define NDIM 4096   // N = 128 blocks * 32
#define NBJ  128    // output block-columns
#define KB   128    // input  block-rows

// ---------------------------------------------------------------------------
// Shared phase-2 body: block-sparse MFMA accumulate for one (rc, j) tile.
// C/D layout: row = quad*4 + reg, col = lane&15 (verified vs CPU ref).
// ---------------------------------------------------------------------------
__device__ __forceinline__ void bsmm_tile(
    const __bf16* __restrict__ xb, const __bf16* __restrict__ wT,
    const int* __restrict__ colptr, const int* __restrict__ colinfo,
    float* __restrict__ y, int M, int rc, int j) {
    int lane = threadIdx.x & 63, wave = threadIdx.x >> 6;
    int quad = lane >> 4, l16 = lane & 15;
    int wrow = rc * 256 + wave * 64;

    int beg = colptr[j], end = colptr[j + 1];
    int cnt = end - beg;

    f32x4 acc[4][2] = {};

    if (cnt > 0) {
        size_t strideA = (size_t)M * 32;                       // elems per ib slab
        const __bf16* xbase = xb + (size_t)(wrow + l16) * 32 + quad * 8;
        const __bf16* wbase = wT + l16 * 32 + quad * 8;
        int cap = cnt - 1;

        if (cnt <= 64) {
            int einfo = colinfo[beg + (lane <= cap ? lane : cap)];
            auto fetch = [&](int p) {
                int pp = p <= cap ? p : cap;
                int ee = __shfl(einfo, pp);
                int n = ee & 0xFFFF, ib = ee >> 16;
                struct { bf16x8 a0, a1, a2, a3, b0, b1; } f;
                const __bf16* xp = xbase + (size_t)ib * strideA;
                f.a0 = *(const bf16x8*)(xp);
                f.a1 = *(const bf16x8*)(xp + 16 * 32);
                f.a2 = *(const bf16x8*)(xp + 32 * 32);
                f.a3 = *(const bf16x8*)(xp + 48 * 32);
                const __bf16* wp = wbase + (size_t)n * 1024;
                f.b0 = *(const bf16x8*)(wp);
                f.b1 = *(const bf16x8*)(wp + 512);
                return f;
            };
            auto f0 = fetch(0);
            auto f1 = fetch(1);
            for (int p = 0; p < cnt; ++p) {
                acc[0][0] = __builtin_amdgcn_mfma_f32_16x16x32_bf16(f0.a0, f0.b0, acc[0][0], 0, 0, 0);
                acc[0][1] = __builtin_amdgcn_mfma_f32_16x16x32_bf16(f0.a0, f0.b1, acc[0][1], 0, 0, 0);
                acc[1][0] = __builtin_amdgcn_mfma_f32_16x16x32_bf16(f0.a1, f0.b0, acc[1][0], 0, 0, 0);
                acc[1][1] = __builtin_amdgcn_mfma_f32_16x16x32_bf16(f0.a1, f0.b1, acc[1][1], 0, 0, 0);
                acc[2][0] = __builtin_amdgcn_mfma_f32_16x16x32_bf16(f0.a2, f0.b0, acc[2][0], 0, 0, 0);
                acc[2][1] = __builtin_amdgcn_mfma_f32_16x16x32_bf16(f0.a2, f0.b1, acc[2][1], 0, 0, 0);
                acc[3][0] = __builtin_amdgcn_mfma_f32_16x16x32_bf16(f0.a3, f0.b0, acc[3][0], 0, 0, 0);
                acc[3][1] = __builtin_amdgcn_mfma_f32_16x16x32_bf16(f0.a3, f0.b1, acc[3][1], 0, 0, 0);
                f0 = f1;
                f1 = fetch(p + 2);
            }
        } else {
            auto fetch = [&](int p) {
                int pp = p <= cap ? p : cap;
                int ee = colinfo[beg + pp];
                int n = ee & 0xFFFF, ib = ee >> 16;
                struct { bf16x8 a0, a1, a2, a3, b0, b1; } f;
                const __bf16* xp = xbase + (size_t)ib * strideA;
                f.a0 = *(const bf16x8*)(xp);
                f.a1 = *(const bf16x8*)(xp + 16 * 32);
                f.a2 = *(const bf16x8*)(xp + 32 * 32);
                f.a3 = *(const bf16x8*)(xp + 48 * 32);
                const __bf16* wp = wbase + (size_t)n * 1024;
                f.b0 = *(const bf16x8*)(wp);
                f.b1 = *(const bf16x8*)(wp + 512);
                return f;
            };
            auto f0 = fetch(0);
            auto f1 = fetch(1);
            for (int p = 0; p < cnt; ++p) {
                acc[0][0] = __builtin_amdgcn_mfma_f32_16x16x32_bf16(f0.a0, f0.b0, acc[0][0], 0, 0, 0);
                acc[0][1] = __builtin_amdgcn_mfma_f32_16x16x32_bf16(f0.a0, f0.b1, acc[0][1], 0, 0, 0);
                acc[1][0] = __builtin_amdgcn_mfma_f32_16x16x32_bf16(f0.a1, f0.b0, acc[1][0], 0, 0, 0);
                acc[1][1] = __builtin_amdgcn_mfma_f32_16x16x32_bf16(f0.a1, f0.b1, acc[1][1], 0, 0, 0);
                acc[2][0] = __builtin_amdgcn_mfma_f32_16x16x32_bf16(f0.a2, f0.b0, acc[2][0], 0, 0, 0);
                acc[2][1] = __builtin_amdgcn_mfma_f32_16x16x32_bf16(f0.a2, f0.b1, acc[2][1], 0, 0, 0);
                acc[3][0] = __builtin_amdgcn_mfma_f32_16x16x32_bf16(f0.a3, f0.b0, acc[3][0], 0, 0, 0);
                acc[3][1] = __builtin_amdgcn_mfma_f32_16x16x32_bf16(f0.a3, f0.b1, acc[3][1], 0, 0, 0);
                f0 = f1;
                f1 = fetch(p + 2);
            }
        }
    }

    #pragma unroll
    for (int r = 0; r < 4; ++r)
        #pragma unroll
        for (int ch = 0; ch < 2; ++ch)
            #pragma unroll
            for (int reg = 0; reg < 4; ++reg) {
                int row = wrow + r * 16 + quad * 4 + reg;
                int col = j * 32 + ch * 16 + l16;
                y[(size_t)row * NDIM + col] = acc[r][ch][reg];
            }
}

// ---------------------------------------------------------------------------
// Fused cooperative kernel: phase 1 (cvt + wtrans + CSC) | grid.sync | phase 2.
// Grid = (M/256)*NBJ = 2048 WGs of 256 thr = exactly 32 waves/CU resident
// (launch_bounds forces VGPR<=64). WG (rc, j) converts the x tile it
// co-locates with on its XCD, so xb stays dirty in the producing L2.
// ---------------------------------------------------------------------------
__global__ __launch_bounds__(256, 8) void k_fused(
    const float* __restrict__ x, const float* __restrict__ w,
    const int* __restrict__ idx_i, const int* __restrict__ idx_j,
    __bf16* __restrict__ xb, __bf16* __restrict__ wT,
    int* __restrict__ colptr, int* __restrict__ colinfo,
    float* __restrict__ y, int nnz, int M) {
    __shared__ char smem[2176];
    int l = blockIdx.x, t = threadIdx.x;
    int RCH = M >> 8;

    int rc, j;
    if ((RCH & 7) == 0) {
        int rps = RCH >> 3;
        int s = l & 7, u = l >> 3;
        rc = s * rps + (u % rps);
        j  = u / rps;
    } else {
        rc = l % RCH; j = l / RCH;
    }

    // ---- phase 1a: x[rc*256..+256, j*32..+32] (fp32) -> xb[i=j][rows] (bf16)
    {
        int q = t & 3, r = t >> 2;
        #pragma unroll
        for (int it = 0; it < 4; ++it) {
            int row = rc * 256 + it * 64 + r;
            const float* xp = x + (size_t)row * KDIM + j * 32 + q * 8;
            float4 u4 = ((const float4*)xp)[0];
            float4 v4 = ((const float4*)xp)[1];
            bf16x8 o;
            o[0]=(__bf16)u4.x; o[1]=(__bf16)u4.y; o[2]=(__bf16)u4.z; o[3]=(__bf16)u4.w;
            o[4]=(__bf16)v4.x; o[5]=(__bf16)v4.y; o[6]=(__bf16)v4.z; o[7]=(__bf16)v4.w;
            *(bf16x8*)(xb + ((size_t)j * M + row) * 32 + q * 8) = o;
        }
    }

    // ---- phase 1b: wT[n][c][k] = bf16(w[n][k][c]), grid-strided over nnz
    for (int n = l; n < nnz; n += gridDim.x) {
        auto tile = (__bf16(*)[33])smem;
        float4 v = ((const float4*)(w + (size_t)n * 1024))[t];
        int e = t * 4, k = e >> 5, c = e & 31;
        tile[k][c + 0] = (__bf16)v.x; tile[k][c + 1] = (__bf16)v.y;
        tile[k][c + 2] = (__bf16)v.z; tile[k][c + 3] = (__bf16)v.w;
        __syncthreads();
        int f = t * 4, cc = f >> 5, kk = f & 31;
        bf16x4 o;
        o[0] = tile[kk + 0][cc]; o[1] = tile[kk + 1][cc];
        o[2] = tile[kk + 2][cc]; o[3] = tile[kk + 3][cc];
        ((bf16x4*)(wT + (size_t)n * 1024))[t] = o;
        __syncthreads();
    }

    // ---- phase 1c: CSC build (last WG): colptr + packed (ib<<16)|n colinfo
    if (l == gridDim.x - 1) {
        int* cnt = (int*)smem;          // [NBJ]
        int* cur = cnt + NBJ;           // [NBJ]
        if (t < NBJ) cnt[t] = 0;
        __syncthreads();
        for (int n = t; n < nnz; n += 256) atomicAdd(&cnt[idx_j[n]], 1);
        __syncthreads();
        int mycount = (t < NBJ) ? cnt[t] : 0;
        for (int off = 1; off < NBJ; off <<= 1) {
            int add = (t < NBJ && t >= off) ? cnt[t - off] : 0;
            __syncthreads();
            if (t < NBJ) cnt[t] += add;
            __syncthreads();
        }
        if (t < NBJ) {
            colptr[t + 1] = cnt[t];
            cur[t] = cnt[t] - mycount;
            if (t == 0) colptr[0] = 0;
        }
        __syncthreads();
        for (int n = t; n < nnz; n += 256) {
            int jj = idx_j[n];
            int pos = atomicAdd(&cur[jj], 1);
            colinfo[pos] = (idx_i[n] << 16) | n;
        }
    }

    cg::this_grid().sync();

    // ---- phase 2: MFMA accumulate
    bsmm_tile(xb, wT, colptr, colinfo, y, M, rc, j);
}

// ---------------------------------------------------------------------------
// Fallback path (identical to previous verified version)
// ---------------------------------------------------------------------------
__global__ __launch_bounds__(256) void k_prep(
    const float* __restrict__ x, const float* __restrict__ w,
    const int* __restrict__ idx_i, const int* __restrict__ idx_j,
    __bf16* __restrict__ xb, __bf16* __restrict__ wT,
    int* __restrict__ colptr, int* __restrict__ colinfo,
    int nnz, int M, int nbCvt) {
    __shared__ char smem[2176];
    int b = blockIdx.x, t = threadIdx.x;

    if (b < nbCvt) {
        int i  = b & (KB - 1);
        int m0 = (b >> 7) * 64;
        int q  = t & 3, r = t >> 2;
        const float* xp = x + (size_t)(m0 + r) * KDIM + i * 32 + q * 8;
        float4 u = ((const float4*)xp)[0];
        float4 v = ((const float4*)xp)[1];
        bf16x8 o;
        o[0]=(__bf16)u.x; o[1]=(__bf16)u.y; o[2]=(__bf16)u.z; o[3]=(__bf16)u.w;
        o[4]=(__bf16)v.x; o[5]=(__bf16)v.y; o[6]=(__bf16)v.z; o[7]=(__bf16)v.w;
        *(bf16x8*)(xb + ((size_t)i * M + m0 + r) * 32 + q * 8) = o;
    } else if (b < nbCvt + nnz) {
        auto tile = (__bf16(*)[33])smem;
        int n = b - nbCvt;
        float4 v = ((const float4*)(w + (size_t)n * 1024))[t];
        int e = t * 4, k = e >> 5, c = e & 31;
        tile[k][c + 0] = (__bf16)v.x; tile[k][c + 1] = (__bf16)v.y;
        tile[k][c + 2] = (__bf16)v.z; tile[k][c + 3] = (__bf16)v.w;
        __syncthreads();
        int f = t * 4, cc = f >> 5, kk = f & 31;
        bf16x4 o;
        o[0] = tile[kk + 0][cc]; o[1] = tile[kk + 1][cc];
        o[2] = tile[kk + 2][cc]; o[3] = tile[kk + 3][cc];
        ((bf16x4*)(wT + (size_t)n * 1024))[t] = o;
    } else {
        int* cnt = (int*)smem;
        int* cur = cnt + NBJ;
        if (t < NBJ) cnt[t] = 0;
        __syncthreads();
        for (int n = t; n < nnz; n += 256) atomicAdd(&cnt[idx_j[n]], 1);
        __syncthreads();
        int mycount = (t < NBJ) ? cnt[t] : 0;
        for (int off = 1; off < NBJ; off <<= 1) {
            int add = (t < NBJ && t >= off) ? cnt[t - off] : 0;
            __syncthreads();
            if (t < NBJ) cnt[t] += add;
            __syncthreads();
        }
        if (t < NBJ) {
            colptr[t + 1] = cnt[t];
            cur[t] = cnt[t] - mycount;
            if (t == 0) colptr[0] = 0;
        }
        __syncthreads();
        for (int n = t; n < nnz; n += 256) {
            int jj = idx_j[n];
            int pos = atomicAdd(&cur[jj], 1);
            colinfo[pos] = (idx_i[n] << 16) | n;
        }
    }
}

__global__ __launch_bounds__(256) void k_bsmm(
    const __bf16* __restrict__ xb, const __bf16* __restrict__ wT,
    const int* __restrict__ colptr, const int* __restrict__ colinfo,
    float* __restrict__ y, int M) {
    int RCH = M >> 8;
    int l = blockIdx.x;
    int rc, j;
    if ((RCH & 7) == 0) {
        int rps = RCH >> 3;
        int s = l & 7, u = l >> 3;
        rc = s * rps + (u % rps);
        j  = u / rps;
    } else {
        rc = l % RCH; j = l / RCH;
    }
    bsmm_tile(xb, wT, colptr, colinfo, y, M, rc, j);
}

__global__ __launch_bounds__(256) void k_bsmm_nows(
    const float* __restrict__ x, const float* __restrict__ w,
    const int* __restrict__ idx_i, const int* __restrict__ idx_j,
    float* __restrict__ y, int nnz) {
    __shared__ int list[256];
    __shared__ int listn;
    __shared__ __bf16 tw[32][40];
    int j = blockIdx.y;
    int tid = threadIdx.x;
    int lane = tid & 63, wave = tid >> 6;
    int quad = lane >> 4, l16 = lane & 15;
    int wrow = blockIdx.x * 256 + wave * 64;

    if (tid == 0) listn = 0;
    __syncthreads();
    for (int n = tid; n < nnz; n += 256)
        if (idx_j[n] == j) { int p = atomicAdd(&listn, 1); list[p & 255] = n; }
    __syncthreads();
    int cnt = listn;

    f32x4 acc[4][2] = {};
    for (int p = 0; p < cnt; ++p) {
        int n = list[p];
        int ib = idx_i[n];
        {
            float4 v = ((const float4*)(w + (size_t)n * 1024))[tid];
            int e = tid * 4, k = e >> 5, c = e & 31;
            tw[c + 0][k] = (__bf16)v.x; tw[c + 1][k] = (__bf16)v.y;
            tw[c + 2][k] = (__bf16)v.z; tw[c + 3][k] = (__bf16)v.w;
        }
        __syncthreads();
        bf16x8 a[4];
        #pragma unroll
        for (int r = 0; r < 4; ++r) {
            const float* xp = x + (size_t)(wrow + r * 16 + l16) * KDIM + ib * 32 + quad * 8;
            float4 u = *(const float4*)(xp);
            float4 v = *(const float4*)(xp + 4);
            a[r][0] = (__bf16)u.x; a[r][1] = (__bf16)u.y; a[r][2] = (__bf16)u.z; a[r][3] = (__bf16)u.w;
            a[r][4] = (__bf16)v.x; a[r][5] = (__bf16)v.y; a[r][6] = (__bf16)v.z; a[r][7] = (__bf16)v.w;
        }
        bf16x8 b0 = *(const bf16x8*)&tw[l16][quad * 8];
        bf16x8 b1 = *(const bf16x8*)&tw[l16 + 16][quad * 8];
        #pragma unroll
        for (int r = 0; r < 4; ++r) {
            acc[r][0] = __builtin_amdgcn_mfma_f32_16x16x32_bf16(a[r], b0, acc[r][0], 0, 0, 0);
            acc[r][1] = __builtin_amdgcn_mfma_f32_16x16x32_bf16(a[r], b1, acc[r][1], 0, 0, 0);
        }
        __syncthreads();
    }

    #pragma unroll
    for (int r = 0; r < 4; ++r)
        #pragma unroll
        for (int ch = 0; ch < 2; ++ch)
            #pragma unroll
            for (int reg = 0; reg < 4; ++reg) {
                int row = wrow + r * 16 + quad * 4 + reg;
                int col = j * 32 + ch * 16 + l16;
                y[(size_t)row * NDIM + col] = acc[r][ch][reg];
            }
}

extern "C" void kernel_launch(void* const* d_in, const int* in_sizes, int n_in,
                              void* d_out, int out_size, void* d_ws, size_t ws_size,
                              hipStream_t stream) {
    const float* x     = (const float*)d_in[0];
    const float* w     = (const float*)d_in[1];
    const int*   idx_i = (const int*)d_in[2];
    const int*   idx_j = (const int*)d_in[3];
    float*       y     = (float*)d_out;

    int nnz = in_sizes[2];
    int M   = in_sizes[0] / KDIM;                   // 4096

    size_t xb_bytes = (size_t)M * KDIM * 2;         // 32 MB
    size_t wt_bytes = (size_t)nnz * 1024 * 2;
    size_t need = xb_bytes + wt_bytes + (size_t)(NBJ + 2 + nnz) * 4;

    if (ws_size >= need && (M & 255) == 0) {
        __bf16* xb      = (__bf16*)d_ws;
        __bf16* wT      = (__bf16*)((char*)d_ws + xb_bytes);
        int*    colptr  = (int*)((char*)d_ws + xb_bytes + wt_bytes);
        int*    colinfo = colptr + NBJ + 1;

        int grid = (M / 256) * NBJ;                 // 2048 — exactly full residency
        void* args[] = {(void*)&x, (void*)&w, (void*)&idx_i, (void*)&idx_j,
                        (void*)&xb, (void*)&wT, (void*)&colptr, (void*)&colinfo,
                        (void*)&y, (void*)&nnz, (void*)&M};
        hipError_t err = hipLaunchCooperativeKernel(
            (const void*)k_fused, dim3(grid), dim3(256), args, 0, stream);
        if (err != hipSuccess) {
            (void)hipGetLastError();                // clear, fall back
            int nbCvt = KB * (M / 64);
            k_prep<<<nbCvt + nnz + 1, 256, 0, stream>>>(x, w, idx_i, idx_j,
                                                        xb, wT, colptr, colinfo,
                                                        nnz, M, nbCvt);
            k_bsmm<<<(M / 256) * NBJ, 256, 0, stream>>>(xb, wT, colptr, colinfo, y, M);
        }
    } else {
        k_bsmm_nows<<<dim3(M / 256, NBJ), 256, 0, stream>>>(x, w, idx_i, idx_j, y, nnz);
    }
}

// Round 2
// 177.152 us; speedup vs baseline: 2.4269x; 2.4269x over previous
//
#include <hip/hip_runtime.h>
#include <hip/hip_bf16.h>

typedef __bf16 bf16x8 __attribute__((ext_vector_type(8)));
typedef __bf16 bf16x4 __attribute__((ext_vector_type(4)));
typedef float f32x4 __attribute__((ext_vector_type(4)));

#define KDIM 4096   // K = 128 blocks * 32
#define NDIM 4096   // N = 128 blocks * 32
#define NBJ  128    // output block-columns
#define KB   128    // input  block-rows

// ---- fused prep: [0, nbCvt) cvt+permute x | [nbCvt, +nnz) wtrans | last: csc
__global__ __launch_bounds__(256) void k_prep(
    const float* __restrict__ x, const float* __restrict__ w,
    const int* __restrict__ idx_i, const int* __restrict__ idx_j,
    __bf16* __restrict__ xb, __bf16* __restrict__ wT,
    int* __restrict__ colptr, int* __restrict__ colinfo,
    int nnz, int M, int nbCvt) {
    __shared__ char smem[2176];
    int b = blockIdx.x, t = threadIdx.x;

    if (b < nbCvt) {
        // xb[i][m][k] = bf16(x[m][i*32+k]); 64 rows per WG
        int i  = b & (KB - 1);
        int m0 = (b >> 7) * 64;
        int q  = t & 3, r = t >> 2;
        const float* xp = x + (size_t)(m0 + r) * KDIM + i * 32 + q * 8;
        float4 u = ((const float4*)xp)[0];
        float4 v = ((const float4*)xp)[1];
        bf16x8 o;
        o[0]=(__bf16)u.x; o[1]=(__bf16)u.y; o[2]=(__bf16)u.z; o[3]=(__bf16)u.w;
        o[4]=(__bf16)v.x; o[5]=(__bf16)v.y; o[6]=(__bf16)v.z; o[7]=(__bf16)v.w;
        *(bf16x8*)(xb + ((size_t)i * M + m0 + r) * 32 + q * 8) = o;
    } else if (b < nbCvt + nnz) {
        // wT[n][c][k] = bf16(w[n][k][c])
        auto tile = (__bf16(*)[33])smem;
        int n = b - nbCvt;
        float4 v = ((const float4*)(w + (size_t)n * 1024))[t];
        int e = t * 4, k = e >> 5, c = e & 31;
        tile[k][c + 0] = (__bf16)v.x; tile[k][c + 1] = (__bf16)v.y;
        tile[k][c + 2] = (__bf16)v.z; tile[k][c + 3] = (__bf16)v.w;
        __syncthreads();
        int f = t * 4, cc = f >> 5, kk = f & 31;
        bf16x4 o;
        o[0] = tile[kk + 0][cc]; o[1] = tile[kk + 1][cc];
        o[2] = tile[kk + 2][cc]; o[3] = tile[kk + 3][cc];
        ((bf16x4*)(wT + (size_t)n * 1024))[t] = o;
    } else {
        // CSC build: colptr + packed (ib<<16)|n colinfo
        int* cnt = (int*)smem;          // [NBJ]
        int* cur = cnt + NBJ;           // [NBJ]
        if (t < NBJ) cnt[t] = 0;
        __syncthreads();
        for (int n = t; n < nnz; n += 256) atomicAdd(&cnt[idx_j[n]], 1);
        __syncthreads();
        int mycount = (t < NBJ) ? cnt[t] : 0;
        for (int off = 1; off < NBJ; off <<= 1) {
            int add = (t < NBJ && t >= off) ? cnt[t - off] : 0;
            __syncthreads();
            if (t < NBJ) cnt[t] += add;
            __syncthreads();
        }
        if (t < NBJ) {
            colptr[t + 1] = cnt[t];
            cur[t] = cnt[t] - mycount;
            if (t == 0) colptr[0] = 0;
        }
        __syncthreads();
        for (int n = t; n < nnz; n += 256) {
            int j = idx_j[n];
            int pos = atomicAdd(&cur[j], 1);
            colinfo[pos] = (idx_i[n] << 16) | n;
        }
    }
}

// ---- main kernel ------------------------------------------------------------
// rc-major XCD decode: each XCD finishes all 128 j's of one 2 MB xb slab
// before moving on (slab stays L2-resident).  3-deep explicit-rotation
// software pipeline: lookahead ~3 sub-iters covers L3/HBM load latency at
// the 3-waves/SIMD occupancy the register footprint allows.
struct Frag { bf16x8 a0, a1, a2, a3, b0, b1; };

#define MFMA8(F)                                                               \
    acc[0][0] = __builtin_amdgcn_mfma_f32_16x16x32_bf16(F.a0, F.b0, acc[0][0], 0, 0, 0); \
    acc[0][1] = __builtin_amdgcn_mfma_f32_16x16x32_bf16(F.a0, F.b1, acc[0][1], 0, 0, 0); \
    acc[1][0] = __builtin_amdgcn_mfma_f32_16x16x32_bf16(F.a1, F.b0, acc[1][0], 0, 0, 0); \
    acc[1][1] = __builtin_amdgcn_mfma_f32_16x16x32_bf16(F.a1, F.b1, acc[1][1], 0, 0, 0); \
    acc[2][0] = __builtin_amdgcn_mfma_f32_16x16x32_bf16(F.a2, F.b0, acc[2][0], 0, 0, 0); \
    acc[2][1] = __builtin_amdgcn_mfma_f32_16x16x32_bf16(F.a2, F.b1, acc[2][1], 0, 0, 0); \
    acc[3][0] = __builtin_amdgcn_mfma_f32_16x16x32_bf16(F.a3, F.b0, acc[3][0], 0, 0, 0); \
    acc[3][1] = __builtin_amdgcn_mfma_f32_16x16x32_bf16(F.a3, F.b1, acc[3][1], 0, 0, 0);

__global__ __launch_bounds__(256) void k_bsmm(
    const __bf16* __restrict__ xb, const __bf16* __restrict__ wT,
    const int* __restrict__ colptr, const int* __restrict__ colinfo,
    float* __restrict__ y, int M) {
    int RCH = M >> 8;
    int l = blockIdx.x;
    int rc, j;
    if ((RCH & 7) == 0) {
        // XCD s (= l%8 by dispatch round-robin) walks: all j of rc slab 0,
        // then all j of rc slab 1, ...
        int rps = RCH >> 3;
        int s = l & 7, u = l >> 3;        // u in [0, rps*NBJ)
        rc = s * rps + (u >> 7);          // u / NBJ
        j  = u & (NBJ - 1);               // u % NBJ
    } else {
        rc = l % RCH; j = l / RCH;
    }
    int lane = threadIdx.x & 63, wave = threadIdx.x >> 6;
    int quad = lane >> 4, l16 = lane & 15;
    int wrow = rc * 256 + wave * 64;

    int beg = colptr[j], end = colptr[j + 1];
    int cnt = end - beg;

    f32x4 acc[4][2] = {};

    if (cnt > 0) {
        size_t strideA = (size_t)M * 32;                       // elems per ib slab
        const __bf16* xbase = xb + (size_t)(wrow + l16) * 32 + quad * 8;
        const __bf16* wbase = wT + l16 * 32 + quad * 8;
        int cap = cnt - 1;

        if (cnt <= 64) {
            int einfo = colinfo[beg + (lane <= cap ? lane : cap)];
            auto fetch = [&](int p) {
                int pp = p <= cap ? p : cap;
                int ee = __shfl(einfo, pp);
                int n = ee & 0xFFFF, ib = ee >> 16;
                Frag f;
                const __bf16* xp = xbase + (size_t)ib * strideA;
                f.a0 = *(const bf16x8*)(xp);
                f.a1 = *(const bf16x8*)(xp + 16 * 32);
                f.a2 = *(const bf16x8*)(xp + 32 * 32);
                f.a3 = *(const bf16x8*)(xp + 48 * 32);
                const __bf16* wp = wbase + (size_t)n * 1024;
                f.b0 = *(const bf16x8*)(wp);
                f.b1 = *(const bf16x8*)(wp + 512);
                return f;
            };
            Frag f0 = fetch(0);
            Frag f1 = fetch(1);
            Frag f2 = fetch(2);
            int p = 0;
            for (; p + 3 <= cnt; p += 3) {
                MFMA8(f0); f0 = fetch(p + 3);
                MFMA8(f1); f1 = fetch(p + 4);
                MFMA8(f2); f2 = fetch(p + 5);
            }
            if (p < cnt)     { MFMA8(f0); }
            if (p + 1 < cnt) { MFMA8(f1); }
            if (p + 2 < cnt) { MFMA8(f2); }
        } else {
            auto fetch = [&](int p) {
                int pp = p <= cap ? p : cap;
                int ee = colinfo[beg + pp];
                int n = ee & 0xFFFF, ib = ee >> 16;
                Frag f;
                const __bf16* xp = xbase + (size_t)ib * strideA;
                f.a0 = *(const bf16x8*)(xp);
                f.a1 = *(const bf16x8*)(xp + 16 * 32);
                f.a2 = *(const bf16x8*)(xp + 32 * 32);
                f.a3 = *(const bf16x8*)(xp + 48 * 32);
                const __bf16* wp = wbase + (size_t)n * 1024;
                f.b0 = *(const bf16x8*)(wp);
                f.b1 = *(const bf16x8*)(wp + 512);
                return f;
            };
            Frag f0 = fetch(0);
            Frag f1 = fetch(1);
            Frag f2 = fetch(2);
            int p = 0;
            for (; p + 3 <= cnt; p += 3) {
                MFMA8(f0); f0 = fetch(p + 3);
                MFMA8(f1); f1 = fetch(p + 4);
                MFMA8(f2); f2 = fetch(p + 5);
            }
            if (p < cnt)     { MFMA8(f0); }
            if (p + 1 < cnt) { MFMA8(f1); }
            if (p + 2 < cnt) { MFMA8(f2); }
        }
    }

    // C/D layout: row = quad*4 + reg, col = lane&15
    #pragma unroll
    for (int r = 0; r < 4; ++r)
        #pragma unroll
        for (int ch = 0; ch < 2; ++ch)
            #pragma unroll
            for (int reg = 0; reg < 4; ++reg) {
                int row = wrow + r * 16 + quad * 4 + reg;
                int col = j * 32 + ch * 16 + l16;
                y[(size_t)row * NDIM + col] = acc[r][ch][reg];
            }
}

// ---- fallback (no workspace): fp32 reads, convert in-kernel -----------------
__global__ __launch_bounds__(256) void k_bsmm_nows(
    const float* __restrict__ x, const float* __restrict__ w,
    const int* __restrict__ idx_i, const int* __restrict__ idx_j,
    float* __restrict__ y, int nnz) {
    __shared__ int list[256];
    __shared__ int listn;
    __shared__ __bf16 tw[32][40];
    int j = blockIdx.y;
    int tid = threadIdx.x;
    int lane = tid & 63, wave = tid >> 6;
    int quad = lane >> 4, l16 = lane & 15;
    int wrow = blockIdx.x * 256 + wave * 64;

    if (tid == 0) listn = 0;
    __syncthreads();
    for (int n = tid; n < nnz; n += 256)
        if (idx_j[n] == j) { int p = atomicAdd(&listn, 1); list[p & 255] = n; }
    __syncthreads();
    int cnt = listn;

    f32x4 acc[4][2] = {};
    for (int p = 0; p < cnt; ++p) {
        int n = list[p];
        int ib = idx_i[n];
        {
            float4 v = ((const float4*)(w + (size_t)n * 1024))[tid];
            int e = tid * 4, k = e >> 5, c = e & 31;
            tw[c + 0][k] = (__bf16)v.x; tw[c + 1][k] = (__bf16)v.y;
            tw[c + 2][k] = (__bf16)v.z; tw[c + 3][k] = (__bf16)v.w;
        }
        __syncthreads();
        bf16x8 a[4];
        #pragma unroll
        for (int r = 0; r < 4; ++r) {
            const float* xp = x + (size_t)(wrow + r * 16 + l16) * KDIM + ib * 32 + quad * 8;
            float4 u = *(const float4*)(xp);
            float4 v = *(const float4*)(xp + 4);
            a[r][0] = (__bf16)u.x; a[r][1] = (__bf16)u.y; a[r][2] = (__bf16)u.z; a[r][3] = (__bf16)u.w;
            a[r][4] = (__bf16)v.x; a[r][5] = (__bf16)v.y; a[r][6] = (__bf16)v.z; a[r][7] = (__bf16)v.w;
        }
        bf16x8 b0 = *(const bf16x8*)&tw[l16][quad * 8];
        bf16x8 b1 = *(const bf16x8*)&tw[l16 + 16][quad * 8];
        #pragma unroll
        for (int r = 0; r < 4; ++r) {
            acc[r][0] = __builtin_amdgcn_mfma_f32_16x16x32_bf16(a[r], b0, acc[r][0], 0, 0, 0);
            acc[r][1] = __builtin_amdgcn_mfma_f32_16x16x32_bf16(a[r], b1, acc[r][1], 0, 0, 0);
        }
        __syncthreads();
    }

    #pragma unroll
    for (int r = 0; r < 4; ++r)
        #pragma unroll
        for (int ch = 0; ch < 2; ++ch)
            #pragma unroll
            for (int reg = 0; reg < 4; ++reg) {
                int row = wrow + r * 16 + quad * 4 + reg;
                int col = j * 32 + ch * 16 + l16;
                y[(size_t)row * NDIM + col] = acc[r][ch][reg];
            }
}

extern "C" void kernel_launch(void* const* d_in, const int* in_sizes, int n_in,
                              void* d_out, int out_size, void* d_ws, size_t ws_size,
                              hipStream_t stream) {
    const float* x     = (const float*)d_in[0];
    const float* w     = (const float*)d_in[1];
    const int*   idx_i = (const int*)d_in[2];
    const int*   idx_j = (const int*)d_in[3];
    float*       y     = (float*)d_out;

    int nnz = in_sizes[2];
    int M   = in_sizes[0] / KDIM;                   // 4096

    size_t xb_bytes = (size_t)M * KDIM * 2;         // 32 MB
    size_t wt_bytes = (size_t)nnz * 1024 * 2;
    size_t need = xb_bytes + wt_bytes + (size_t)(NBJ + 2 + nnz) * 4;

    if (ws_size >= need && (M & 255) == 0) {
        __bf16* xb      = (__bf16*)d_ws;
        __bf16* wT      = (__bf16*)((char*)d_ws + xb_bytes);
        int*    colptr  = (int*)((char*)d_ws + xb_bytes + wt_bytes);
        int*    colinfo = colptr + NBJ + 1;
        int nbCvt = KB * (M / 64);                  // 8192
        k_prep<<<nbCvt + nnz + 1, 256, 0, stream>>>(x, w, idx_i, idx_j,
                                                    xb, wT, colptr, colinfo,
                                                    nnz, M, nbCvt);
        k_bsmm<<<(M / 256) * NBJ, 256, 0, stream>>>(xb, wT, colptr, colinfo, y, M);
    } else {
        k_bsmm_nows<<<dim3(M / 256, NBJ), 256, 0, stream>>>(x, w, idx_i, idx_j, y, nnz);
    }
}